// Round 9
// baseline (839.112 us; speedup 1.0000x reference)
//
#include <hip/hip_runtime.h>

typedef unsigned int u32;
typedef unsigned short u16;
typedef _Float16 f16x2 __attribute__((ext_vector_type(2)));

// ---------------- problem constants ----------------
// B=32, T=32, F=64, H=256, N=1024, A=64, C=192, M=256
// out: hs [32,256,32] (262144 f32) then outs [32,10,32] (10240 f32)

// ---------------- workspace (u32 offsets): i8 panels, chunk16 layout [chunk][64] uint4 ----
#define WP_A0    0        // [Wh0;Wi0] 4p x 20c (k: h 0..255, x 256..319)
#define WP_A1    20480    // [Wh1;Wi1] 4p x 20c
#define WP_A2H   40960    // Wh2 4p x 16c
#define WP_A2I   57344    // Wi2 4p x 4c
#define WP_AQ    61440    // Wq  4p x 16c
#define WP_AC    77824    // [Wch;Wci] 3p x 20c
#define WP_AM    93184    // Wm 12p x 16c (gate-major)
#define WP_AT2   142336   // maddr rows: 16p x 4c (out n, k a)
#define WP_M4    158720   // maddr cols: 64c (out a, k n)
#define WP_WO4   175104   // W_output f16: [10][32] uint4
#define WP_X8    176384   // x i8: [t*32+b][16 u32]
#define WP_SXT   192768   // f32 s_x[t*32+b] (1024)
#define WP_SC    193792   // f32 per-out-column scales (3328)
// scale bases (float index into WP_SC)
#define SC_A0   0
#define SC_A1   256
#define SC_A2H  512
#define SC_A2I  768
#define SC_AQ   1024
#define SC_AC   1280
#define SC_AM   1472
#define SC_AT2  2240
#define SC_M4   3264

// ---------------- LDS layout (f32 offsets) ----------------
#define SH_HX    0      // f32 h[256]
#define SH_H2    256    // u32[128] h f16 pairs (logits)
#define SH_CH8   384    // u32[80] i8 coef: h 0..63, x 64..79
#define SH_Q     464    // f32 q[256] (incl bq)
#define SH_Q8    720    // u32[16] q[0..63] i8
#define SH_GA0   736    // f32 [256]
#define SH_GA1   992    // f32 [256]
#define SH_GH2   1248   // f32 [256]
#define SH_GI2   1504   // f32 [256]
#define SH_GM    1760   // f32 [3][256]
#define SH_SIMA  2528   // f32 [1024]
#define SH_RD    3552   // f32 [256] raw reading
#define SH_D     3808   // f32 [32]
#define SH_G     3840   // f32 [32]
#define SH_RED   3872   // f32 [16]
#define SH_RED2  3888   // f32 [16]
#define SH_RMX   3904   // f32 [8]
#define SH_MISC  3912   // f32 [8]: [0]=beta [1]=s_r [2]=s_x [3]=s_q
#define SH_B10   3920   // f32 [16]
#define SH_RA    3936   // f32 [8][64]
#define SH_E8    4448   // u32 [256] e-row i8
#define SH_R8    4704   // u32 [64] reading i8
#define SH_CAND  4768   // u16[32*192] = 3072 slots
#define SH_W     7840   // u16[32][1024] = 16384 slots
#define SMEM_FLOATS 24224
#define SMEM_BYTES (SMEM_FLOATS*4)

#define WRED(v) { v += __shfl_xor(v,32); v += __shfl_xor(v,16); v += __shfl_xor(v,8); \
                  v += __shfl_xor(v,4);  v += __shfl_xor(v,2);  v += __shfl_xor(v,1); }
#define WMAX(v) { v = fmaxf(v,__shfl_xor(v,32)); v = fmaxf(v,__shfl_xor(v,16)); \
                  v = fmaxf(v,__shfl_xor(v,8));  v = fmaxf(v,__shfl_xor(v,4)); \
                  v = fmaxf(v,__shfl_xor(v,2));  v = fmaxf(v,__shfl_xor(v,1)); }

__device__ __forceinline__ f16x2 bch2(u32 u) { return __builtin_bit_cast(f16x2, u); }

#if __has_builtin(__builtin_amdgcn_fdot2)
__device__ __forceinline__ float FDOT2(u32 a, u32 b, float c) {
  return __builtin_amdgcn_fdot2(bch2(a), bch2(b), c, false);
}
#else
__device__ __forceinline__ float FDOT2(u32 a, u32 b, float c) {
  f16x2 x = bch2(a), y = bch2(b);
  return c + (float)x[0]*(float)y[0] + (float)x[1]*(float)y[1];
}
#endif

#if __has_builtin(__builtin_amdgcn_sdot4)
__device__ __forceinline__ int SDOT4(u32 a, u32 b, int c) {
  return __builtin_amdgcn_sdot4((int)a, (int)b, c, false);
}
#else
__device__ __forceinline__ int SDOT4(u32 a, u32 b, int c) {
  return c + (int)(signed char)(a & 255u)       * (int)(signed char)(b & 255u)
           + (int)(signed char)((a>>8) & 255u)  * (int)(signed char)((b>>8) & 255u)
           + (int)(signed char)((a>>16) & 255u) * (int)(signed char)((b>>16) & 255u)
           + (int)(signed char)(a>>24)          * (int)(signed char)(b>>24);
}
#endif

__device__ __forceinline__ u16 f2h(float x) {
  _Float16 h = (_Float16)x; return __builtin_bit_cast(u16, h);
}
__device__ __forceinline__ float h2f(u16 u) {
  return (float)__builtin_bit_cast(_Float16, u);
}
__device__ __forceinline__ u32 packh2(float lo, float hi) {
  return (u32)f2h(lo) | ((u32)f2h(hi) << 16);
}

// ---- i8 matvec, 1 out/lane. W: [chunk16][64] uint4 (16 i8/lane-load); c: i8 in LDS
// (uint4 per chunk). Groups of 4 chunks, 2-group lookahead (round-4 proven skeleton).
// Dual accumulators: first NGA groups -> accA (scale A), rest -> accB (scale B).
template<int NGA, int NGB>
__device__ __forceinline__ float2 mv_i8(const u32* __restrict__ Wb,
                                        const u32* __restrict__ c2, const int ln)
{
  constexpr int NG = NGA + NGB;
  const uint4* __restrict__ wp = (const uint4*)Wb + ln;
  const uint4* __restrict__ c4 = (const uint4*)c2;
  int aA = 0, aB = 0;
  uint4 wa0, wa1, wa2, wa3, ca0, ca1, ca2, ca3;
  uint4 wb0, wb1, wb2, wb3, cb0, cb1, cb2, cb3;
#define LGA_(g) { wa0 = wp[(g)*256]; wa1 = wp[(g)*256+64]; wa2 = wp[(g)*256+128]; wa3 = wp[(g)*256+192]; \
                  ca0 = c4[(g)*4]; ca1 = c4[(g)*4+1]; ca2 = c4[(g)*4+2]; ca3 = c4[(g)*4+3]; }
#define LGB_(g) { wb0 = wp[(g)*256]; wb1 = wp[(g)*256+64]; wb2 = wp[(g)*256+128]; wb3 = wp[(g)*256+192]; \
                  cb0 = c4[(g)*4]; cb1 = c4[(g)*4+1]; cb2 = c4[(g)*4+2]; cb3 = c4[(g)*4+3]; }
#define CMA_(ACC) { ACC=SDOT4(wa0.x,ca0.x,ACC); ACC=SDOT4(wa0.y,ca0.y,ACC); ACC=SDOT4(wa0.z,ca0.z,ACC); ACC=SDOT4(wa0.w,ca0.w,ACC); \
                    ACC=SDOT4(wa1.x,ca1.x,ACC); ACC=SDOT4(wa1.y,ca1.y,ACC); ACC=SDOT4(wa1.z,ca1.z,ACC); ACC=SDOT4(wa1.w,ca1.w,ACC); \
                    ACC=SDOT4(wa2.x,ca2.x,ACC); ACC=SDOT4(wa2.y,ca2.y,ACC); ACC=SDOT4(wa2.z,ca2.z,ACC); ACC=SDOT4(wa2.w,ca2.w,ACC); \
                    ACC=SDOT4(wa3.x,ca3.x,ACC); ACC=SDOT4(wa3.y,ca3.y,ACC); ACC=SDOT4(wa3.z,ca3.z,ACC); ACC=SDOT4(wa3.w,ca3.w,ACC); }
#define CMB_(ACC) { ACC=SDOT4(wb0.x,cb0.x,ACC); ACC=SDOT4(wb0.y,cb0.y,ACC); ACC=SDOT4(wb0.z,cb0.z,ACC); ACC=SDOT4(wb0.w,cb0.w,ACC); \
                    ACC=SDOT4(wb1.x,cb1.x,ACC); ACC=SDOT4(wb1.y,cb1.y,ACC); ACC=SDOT4(wb1.z,cb1.z,ACC); ACC=SDOT4(wb1.w,cb1.w,ACC); \
                    ACC=SDOT4(wb2.x,cb2.x,ACC); ACC=SDOT4(wb2.y,cb2.y,ACC); ACC=SDOT4(wb2.z,cb2.z,ACC); ACC=SDOT4(wb2.w,cb2.w,ACC); \
                    ACC=SDOT4(wb3.x,cb3.x,ACC); ACC=SDOT4(wb3.y,cb3.y,ACC); ACC=SDOT4(wb3.z,cb3.z,ACC); ACC=SDOT4(wb3.w,cb3.w,ACC); }
  LGA_(0);
  if constexpr (NG == 1) {
    if constexpr (0 < NGA) { CMA_(aA); } else { CMA_(aB); }
  } else {
    LGB_(1);
    #pragma unroll
    for (int g = 0; g + 2 < NG; ++g) {
      if ((g & 1) == 0) { if (g < NGA) { CMA_(aA); } else { CMA_(aB); } LGA_(g + 2); }
      else              { if (g < NGA) { CMB_(aA); } else { CMB_(aB); } LGB_(g + 2); }
    }
    if constexpr (((NG - 2) & 1) == 0) {
      if constexpr (NG - 2 < NGA) { CMA_(aA); } else { CMA_(aB); }
      if constexpr (NG - 1 < NGA) { CMB_(aA); } else { CMB_(aB); }
    } else {
      if constexpr (NG - 2 < NGA) { CMB_(aA); } else { CMB_(aB); }
      if constexpr (NG - 1 < NGA) { CMA_(aA); } else { CMA_(aB); }
    }
  }
#undef LGA_
#undef LGB_
#undef CMA_
#undef CMB_
  return make_float2((float)aA, (float)aB);
}

__device__ __forceinline__ void out_lse(const float* __restrict__ b10,
    float* __restrict__ out, const int t_out, const int bb, const int ln)
{
  float v = (ln < 10) ? b10[ln] : -1e30f;
  float m = v;
  m = fmaxf(m, __shfl_xor(m, 8, 16));
  m = fmaxf(m, __shfl_xor(m, 4, 16));
  m = fmaxf(m, __shfl_xor(m, 2, 16));
  m = fmaxf(m, __shfl_xor(m, 1, 16));
  float e = (ln < 10) ? __expf(v - m) : 0.f;
  float s = e;
  s += __shfl_xor(s, 8, 16);
  s += __shfl_xor(s, 4, 16);
  s += __shfl_xor(s, 2, 16);
  s += __shfl_xor(s, 1, 16);
  if (ln < 10) out[262144 + t_out * 320 + ln * 32 + bb] = v - m - logf(s);
}

// ---------------- pack kernel: symmetric per-column i8 ----------------
__global__ void pack_weights(const float* __restrict__ batch,
                             const float* __restrict__ Wi, const float* __restrict__ Wh,
                             const float* __restrict__ Wm, const float* __restrict__ Wq,
                             const float* __restrict__ Wch, const float* __restrict__ Wci,
                             const float* __restrict__ maddr, const float* __restrict__ Wo,
                             u32* __restrict__ wsu)
{
  const int b = blockIdx.x, tid = threadIdx.x;
  if (b == 52) {  // WO4 f16 + X8 i8
    uint4* d4 = (uint4*)(wsu + WP_WO4);
    for (int idx = tid; idx < 320; idx += 256) {
      const int j = idx >> 5, l = idx & 31;
      const float* s = Wo + j*256 + l*8;
      uint4 v;
      v.x = packh2(s[0], s[1]); v.y = packh2(s[2], s[3]);
      v.z = packh2(s[4], s[5]); v.w = packh2(s[6], s[7]);
      d4[idx] = v;
    }
    float* sxt = (float*)(wsu + WP_SXT);
    for (int p = tid; p < 1024; p += 256) {
      const int t = p >> 5, bb = p & 31;
      float mx = 0.f;
      for (int f2 = 0; f2 < 64; ++f2) {
        const int i2 = f2*32 + bb;
        mx = fmaxf(mx, fabsf(batch[(i2 >> 6)*2048 + t*64 + (i2 & 63)]));
      }
      const float s = fmaxf(mx*(1.0f/127.0f), 1e-20f), rs = 1.0f/s;
      sxt[p] = s;
      for (int j = 0; j < 16; ++j) {
        u32 w = 0;
        #pragma unroll
        for (int i = 0; i < 4; ++i) {
          const int i2 = (j*4 + i)*32 + bb;
          const float v = batch[(i2 >> 6)*2048 + t*64 + (i2 & 63)];
          int qi = (int)rintf(v*rs); qi = qi > 127 ? 127 : (qi < -127 ? -127 : qi);
          w |= (u32)(qi & 255) << (8*i);
        }
        wsu[WP_X8 + p*16 + j] = w;
      }
    }
    return;
  }
  const float *srcA = nullptr, *srcB = nullptr;
  int KA = 0, KB = 0, Ktot = 0, o0 = 0, scb = 0;
  u32* dst = nullptr; bool colmode = false;
  if (b < 4)       { srcA=Wh;         KA=256; srcB=Wi;         KB=64; Ktot=320; o0=b*64;
                     dst=wsu+WP_A0 + b*5120;        scb=SC_A0  + b*64; }
  else if (b < 8)  { srcA=Wh+65536;   KA=256; srcB=Wi+16384;   KB=64; Ktot=320; o0=(b-4)*64;
                     dst=wsu+WP_A1 + (b-4)*5120;    scb=SC_A1  + (b-4)*64; }
  else if (b < 12) { srcA=Wh+131072;  KA=256; Ktot=256; o0=(b-8)*64;
                     dst=wsu+WP_A2H + (b-8)*4096;   scb=SC_A2H + (b-8)*64; }
  else if (b < 16) { srcA=Wi+32768;   KA=64;  Ktot=64;  o0=(b-12)*64;
                     dst=wsu+WP_A2I + (b-12)*1024;  scb=SC_A2I + (b-12)*64; }
  else if (b < 20) { srcA=Wq;         KA=256; Ktot=256; o0=(b-16)*64;
                     dst=wsu+WP_AQ + (b-16)*4096;   scb=SC_AQ  + (b-16)*64; }
  else if (b < 23) { srcA=Wch;        KA=256; srcB=Wci;        KB=64; Ktot=320; o0=(b-20)*64;
                     dst=wsu+WP_AC + (b-20)*5120;   scb=SC_AC  + (b-20)*64; }
  else if (b < 35) { const int x = b-23;
                     srcA=Wm + (x>>2)*65536; KA=256; Ktot=256; o0=(x&3)*64;
                     dst=wsu+WP_AM + x*4096;        scb=SC_AM  + x*64; }
  else if (b < 51) { srcA=maddr;      KA=64;  Ktot=64;  o0=(b-35)*64;
                     dst=wsu+WP_AT2 + (b-35)*1024;  scb=SC_AT2 + (b-35)*64; }
  else             { srcA=maddr;      KA=1024; Ktot=1024; o0=0; colmode=true;
                     dst=wsu+WP_M4;                 scb=SC_M4; }

  const int o = tid & 63, q = tid >> 6, kq = Ktot >> 2;
  float mx = 0.f;
  for (int k = q*kq; k < (q+1)*kq; ++k) {
    const float v = colmode ? srcA[(size_t)k*64 + o]
                  : ((k < KA) ? srcA[(size_t)(o0+o)*KA + k]
                              : srcB[(size_t)(o0+o)*KB + (k - KA)]);
    mx = fmaxf(mx, fabsf(v));
  }
  __shared__ float smx[4][64], sS[64];
  smx[q][o] = mx;
  __syncthreads();
  if (tid < 64) {
    const float m = fmaxf(fmaxf(smx[0][tid], smx[1][tid]), fmaxf(smx[2][tid], smx[3][tid]));
    const float s = fmaxf(m*(1.0f/127.0f), 1e-20f);
    sS[tid] = s;
    ((float*)(wsu + WP_SC))[scb + tid] = s;
  }
  __syncthreads();
  const float rs = 1.0f / sS[o];
  uint4* d4 = (uint4*)dst;
  const int cpq = (Ktot >> 4) >> 2;  // chunks per quarter
  for (int cc = q*cpq; cc < (q+1)*cpq; ++cc) {
    u32 wd0 = 0, wd1 = 0, wd2 = 0, wd3 = 0;
    #pragma unroll
    for (int j = 0; j < 16; ++j) {
      const int k = cc*16 + j;
      const float v = colmode ? srcA[(size_t)k*64 + o]
                    : ((k < KA) ? srcA[(size_t)(o0+o)*KA + k]
                                : srcB[(size_t)(o0+o)*KB + (k - KA)]);
      int qi = (int)rintf(v*rs); qi = qi > 127 ? 127 : (qi < -127 ? -127 : qi);
      const u32 by = (u32)(qi & 255) << ((j & 3)*8);
      if (j < 4) wd0 |= by; else if (j < 8) wd1 |= by;
      else if (j < 12) wd2 |= by; else wd3 |= by;
    }
    d4[cc*64 + o] = make_uint4(wd0, wd1, wd2, wd3);
  }
}

// ---------------- main persistent per-batch kernel ----------------
__global__ __launch_bounds__(1024) void dntm_step(
    const float* __restrict__ bi, const float* __restrict__ bh,
    const float* __restrict__ bm, const float* __restrict__ bo,
    const float* __restrict__ bq, const float* __restrict__ usharp,
    const u32* __restrict__ wsu, float* __restrict__ out)
{
  extern __shared__ float sm[];
  u32* h2u   = (u32*)(sm + SH_H2);
  u32* CH8u  = (u32*)(sm + SH_CH8);
  u32* Q8u   = (u32*)(sm + SH_Q8);
  u32* E8u   = (u32*)(sm + SH_E8);
  u32* R8u   = (u32*)(sm + SH_R8);
  u16* candh = (u16*)(sm + SH_CAND);
  u16* SW16  = (u16*)(sm + SH_W);
  u32* SW32  = (u32*)(sm + SH_W);
  const float* SCf = (const float*)(wsu + WP_SC);
  const float* SXT = (const float*)(wsu + WP_SXT);
  const int tid = threadIdx.x, ln = tid & 63, wv = tid >> 6;
  const int bb = blockIdx.x;
  const float S_H = 1.0f/127.0f;

  if (tid < 256) sm[SH_HX + tid] = 0.f;
  if (tid < 128) h2u[tid] = 0u;
  if (tid < 64) CH8u[tid] = 0u;                 // h i8 = 0
  if (tid >= 64 && tid < 80) CH8u[tid] = wsu[WP_X8 + bb*16 + (tid - 64)];  // x_0
  if (tid == 80) sm[SH_MISC + 2] = SXT[bb];
  __syncthreads();

  for (int t = 0; t < 32; ++t) {
    const float sx = sm[SH_MISC + 2];
    // ===== P1: h/x matvecs (i8 dot4) =====
    if (wv < 4) {
      const float2 f = mv_i8<4,1>(wsu + WP_A0 + wv*5120, CH8u, ln);
      sm[SH_GA0 + wv*64 + ln] = SCf[SC_A0 + wv*64 + ln] * (S_H*f.x + sx*f.y);
    } else if (wv < 8) {
      const int p = wv - 4;
      const float2 f = mv_i8<4,1>(wsu + WP_A1 + p*5120, CH8u, ln);
      sm[SH_GA1 + p*64 + ln] = SCf[SC_A1 + p*64 + ln] * (S_H*f.x + sx*f.y);
    } else if (wv < 11) {
      const int p = wv - 8;
      const float2 f = mv_i8<4,1>(wsu + WP_AC + p*5120, CH8u, ln);
      const float cv = SCf[SC_AC + p*64 + ln] * (S_H*f.x + sx*f.y);
      candh[t*192 + p*64 + ln] = f2h(fmaxf(cv, 0.f));
    } else if (wv == 11) {
      const float2 f = mv_i8<4,0>(wsu + WP_A2H, CH8u, ln);
      sm[SH_GH2 + ln] = SCf[SC_A2H + ln] * S_H * f.x;
    } else {
      const int p = wv - 12;
      const float2 f = mv_i8<4,0>(wsu + WP_AQ + p*4096, CH8u, ln);
      const float qv = SCf[SC_AQ + p*64 + ln] * S_H * f.x + bq[p*64 + ln];
      sm[SH_Q + p*64 + ln] = qv;
      if (wv == 12) {
        // quantize q[0..63] (wave-local max)
        float m = fabsf(qv);
        WMAX(m);
        const float sq = fmaxf(m*(1.0f/127.0f), 1e-20f);
        int qq = (int)rintf(qv / sq);
        const int q1 = __shfl_down(qq, 1), q2 = __shfl_down(qq, 2), q3 = __shfl_down(qq, 3);
        if (!(ln & 3))
          Q8u[ln >> 2] = (u32)((qq & 255) | ((q1 & 255) << 8) | ((q2 & 255) << 16) | ((q3 & 255) << 24));
        if (!ln) sm[SH_MISC + 3] = sq;
        // beta = softplus(u.h) + 1
        const float4 h4 = *(const float4*)(sm + SH_HX + ln*4);
        const float4 u4 = *(const float4*)(usharp + ln*4);
        float v = h4.x*u4.x + h4.y*u4.y + h4.z*u4.z + h4.w*u4.w;
        WRED(v);
        if (!ln) sm[SH_MISC] = fmaxf(v, 0.f) + log1pf(expf(-fabsf(v))) + 1.f;
      } else if (wv == 13) {
        if (t > 0) { // logits of h_t == h_new(t-1) (f16)
          const uint4 ch = ((const uint4*)h2u)[ln & 31];
          const uint4* wo4 = (const uint4*)(wsu + WP_WO4);
          for (int j = 0; j < 10; ++j) {
            float lv = 0.f;
            if (ln < 32) {
              const uint4 w4 = wo4[j*32 + ln];
              lv = FDOT2(w4.x, ch.x, lv); lv = FDOT2(w4.y, ch.y, lv);
              lv = FDOT2(w4.z, ch.z, lv); lv = FDOT2(w4.w, ch.w, lv);
            }
            WRED(lv);
            if (!ln) sm[SH_B10 + j] = lv + bo[j];
          }
        }
      } else {
        const int pi = (wv - 14)*2;  // A2I panels: wv14 -> 0,1 ; wv15 -> 2,3
        float2 g0 = mv_i8<0,1>(wsu + WP_A2I + pi*1024, CH8u + 64, ln);
        sm[SH_GI2 + pi*64 + ln] = SCf[SC_A2I + pi*64 + ln] * sx * g0.y;
        g0 = mv_i8<0,1>(wsu + WP_A2I + (pi+1)*1024, CH8u + 64, ln);
        sm[SH_GI2 + (pi+1)*64 + ln] = SCf[SC_A2I + (pi+1)*64 + ln] * sx * g0.y;
      }
    }
    __syncthreads();

    // ===== P2: sim addr (i8 AT2 x i8 q); A2H p1-3; d[s]; out_lse(t-1) =====
    if (wv < 8) {
      const float sq = sm[SH_MISC + 3];
      float2 f = mv_i8<1,0>(wsu + WP_AT2 + (2*wv)*1024, Q8u, ln);
      sm[SH_SIMA + (2*wv)*64 + ln] = SCf[SC_AT2 + (2*wv)*64 + ln] * sq * f.x;
      f = mv_i8<1,0>(wsu + WP_AT2 + (2*wv+1)*1024, Q8u, ln);
      sm[SH_SIMA + (2*wv+1)*64 + ln] = SCf[SC_AT2 + (2*wv+1)*64 + ln] * sq * f.x;
    } else if (wv < 11) {
      const int p = wv - 7;  // panels 1..3
      const float2 f = mv_i8<4,0>(wsu + WP_A2H + p*4096, CH8u, ln);
      sm[SH_GH2 + p*64 + ln] = SCf[SC_A2H + p*64 + ln] * S_H * f.x;
    } else if (wv < 15) {
      const float q0 = sm[SH_Q + 64 + ln], q1 = sm[SH_Q + 128 + ln], q2 = sm[SH_Q + 192 + ln];
      for (int s = wv - 11; s < t; s += 4) {
        float a2 = h2f(candh[s*192 + ln]) * q0
                 + h2f(candh[s*192 + 64 + ln]) * q1
                 + h2f(candh[s*192 + 128 + ln]) * q2;
        WRED(a2);
        if (!ln) sm[SH_D + s] = a2;
      }
    } else {
      if (t > 0) out_lse(sm + SH_B10, out, t - 1, bb, ln);
    }
    __syncthreads();

    // ===== P3: v = beta*(sim_a + sum_s d[s] w_s[n]); wave max =====
    const int n3 = wv * 64 + ln;
    float v = sm[SH_SIMA + n3];
    #pragma unroll 4
    for (int s = 0; s < t; ++s) v = fmaf(sm[SH_D + s], h2f(SW16[s*1024 + n3]), v);
    v *= sm[SH_MISC];
    {
      float mx = v;
      WMAX(mx);
      if (!ln) sm[SH_RED + wv] = mx;
    }
    __syncthreads();

    // ===== P4: e = exp(v-gmax) -> f16 row + i8 row; wave sums =====
    {
      float gmx = sm[SH_RED];
      #pragma unroll
      for (int i = 1; i < 16; ++i) gmx = fmaxf(gmx, sm[SH_RED + i]);
      const float e = __expf(v - gmx);
      SW16[t*1024 + n3] = f2h(e);
      const int qe = (int)rintf(e * 127.0f);
      const int e1 = __shfl_down(qe, 1), e2 = __shfl_down(qe, 2), e3 = __shfl_down(qe, 3);
      if (!(ln & 3)) E8u[n3 >> 2] = (u32)(qe | (e1 << 8) | (e2 << 16) | (e3 << 24));
      float s2 = e; WRED(s2);
      if (!ln) sm[SH_RED2 + wv] = s2;
    }
    __syncthreads();

    // ===== P5: reading_a raw partials (i8 M4 x i8 e); g[s] = w_s . w_t (f16) =====
    if (wv < 8) {
      const float2 f = mv_i8<2,0>(wsu + WP_M4 + wv*2048, E8u + wv*32, ln);
      sm[SH_RA + wv*64 + ln] = f.x;
    } else {
      float tot = 0.f;
      #pragma unroll
      for (int i = 0; i < 16; ++i) tot += sm[SH_RED2 + i];
      const float inv = 1.0f / tot;
      const uint4 ea = ((const uint4*)(SW32 + t*512))[ln*2];
      const uint4 eb = ((const uint4*)(SW32 + t*512))[ln*2 + 1];
      for (int s = wv - 8; s < t; s += 8) {
        const uint4 wa = ((const uint4*)(SW32 + s*512))[ln*2];
        const uint4 wb = ((const uint4*)(SW32 + s*512))[ln*2 + 1];
        float a2 = 0.f;
        a2 = FDOT2(ea.x, wa.x, a2); a2 = FDOT2(ea.y, wa.y, a2);
        a2 = FDOT2(ea.z, wa.z, a2); a2 = FDOT2(ea.w, wa.w, a2);
        a2 = FDOT2(eb.x, wb.x, a2); a2 = FDOT2(eb.y, wb.y, a2);
        a2 = FDOT2(eb.z, wb.z, a2); a2 = FDOT2(eb.w, wb.w, a2);
        WRED(a2);
        if (!ln) sm[SH_G + s] = a2 * inv;
      }
    }
    __syncthreads();

    // ===== P6: assemble raw reading -> SH_RD + per-wave max =====
    if (wv < 4) {
      float tot = 0.f;
      #pragma unroll
      for (int i = 0; i < 16; ++i) tot += sm[SH_RED2 + i];
      const float inv = 1.0f / tot;
      float r;
      if (wv == 0) {
        float rs2 = 0.f;
        #pragma unroll
        for (int j = 0; j < 8; ++j) rs2 += sm[SH_RA + j*64 + ln];
        r = rs2 * SCf[SC_M4 + ln] * (S_H * inv);   // s_a * s_e(=1/127) * inv
      } else {
        const int c = (wv - 1)*64 + ln;
        float rc = 0.f;
        for (int s = 0; s < t; ++s) rc = fmaf(h2f(candh[s*192 + c]), sm[SH_G + s], rc);
        r = rc;
      }
      sm[SH_RD + wv*64 + ln] = r;
      float m = fabsf(r);
      WMAX(m);
      if (!ln) sm[SH_RMX + wv] = m;
    }
    __syncthreads();

    // ===== P6b: quantize reading -> R8 (one wave) =====
    if (wv == 0) {
      const float mr = fmaxf(fmaxf(sm[SH_RMX], sm[SH_RMX+1]), fmaxf(sm[SH_RMX+2], sm[SH_RMX+3]));
      const float sr = fmaxf(mr*(1.0f/127.0f), 1e-20f);
      const int b0 = (int)rintf(sm[SH_RD + ln*4    ] / sr);
      const int b1 = (int)rintf(sm[SH_RD + ln*4 + 1] / sr);
      const int b2 = (int)rintf(sm[SH_RD + ln*4 + 2] / sr);
      const int b3 = (int)rintf(sm[SH_RD + ln*4 + 3] / sr);
      R8u[ln] = (u32)((b0 & 255) | ((b1 & 255) << 8) | ((b2 & 255) << 16) | ((b3 & 255) << 24));
      if (!ln) sm[SH_MISC + 1] = sr;
    }
    __syncthreads();

    // ===== P7: gm = Wm @ reading (i8); normalize w row; prefetch x =====
    if (wv < 12) {
      const float2 f = mv_i8<4,0>(wsu + WP_AM + wv*4096, R8u, ln);
      sm[SH_GM + (wv>>2)*256 + (wv&3)*64 + ln] =
        SCf[SC_AM + wv*64 + ln] * sm[SH_MISC + 1] * f.x;
    } else if (wv == 12) {
      if (t < 31) {
        if (ln < 16) CH8u[64 + ln] = wsu[WP_X8 + ((t+1)*32 + bb)*16 + ln];
        if (ln == 16) sm[SH_MISC + 2] = SXT[(t+1)*32 + bb];
      }
    } else if (wv >= 14) {
      float tot = 0.f;
      #pragma unroll
      for (int i = 0; i < 16; ++i) tot += sm[SH_RED2 + i];
      const float inv = 1.0f / tot;
      u32* pw = SW32 + t*512 + (wv - 14)*256 + ln*4;
      uint4 v4 = *(const uint4*)pw;
      v4.x = packh2(h2f(v4.x & 0xffff)*inv, h2f(v4.x >> 16)*inv);
      v4.y = packh2(h2f(v4.y & 0xffff)*inv, h2f(v4.y >> 16)*inv);
      v4.z = packh2(h2f(v4.z & 0xffff)*inv, h2f(v4.z >> 16)*inv);
      v4.w = packh2(h2f(v4.w & 0xffff)*inv, h2f(v4.w >> 16)*inv);
      *(uint4*)pw = v4;
    }
    __syncthreads();

    // ===== P8: gates, h update, outputs, h packs (f32 / f16 / i8) =====
    if (tid < 256) {
      const int h = tid;
      const float g0 = sm[SH_GA0 + h] + bi[h]       + bh[h]       + sm[SH_GM + h]       + bm[h];
      const float g1 = sm[SH_GA1 + h] + bi[256 + h] + bh[256 + h] + sm[SH_GM + 256 + h] + bm[256 + h];
      const float gh2v = sm[SH_GH2 + h] + bh[512 + h];
      const float gi2v = sm[SH_GI2 + h] + bi[512 + h];
      const float gm2  = sm[SH_GM + 512 + h] + bm[512 + h];
      const float r = 1.f / (1.f + __expf(-g0));
      const float z = 1.f / (1.f + __expf(-g1));
      const float nn = tanhf(gi2v + gm2 + r * gh2v);
      const float hn = (1.f - z) * nn + z * sm[SH_HX + h];
      sm[SH_HX + h] = hn;
      out[t*8192 + h*32 + bb] = hn;
      const float hn1 = __shfl_down(hn, 1);
      if (!(tid & 1)) h2u[tid >> 1] = packh2(hn, hn1);
      const int qh = (int)rintf(hn * 127.0f);  // |h| < 1 always (GRU)
      const int h1 = __shfl_down(qh, 1), h2 = __shfl_down(qh, 2), h3 = __shfl_down(qh, 3);
      if (!(tid & 3))
        CH8u[tid >> 2] = (u32)((qh & 255) | ((h1 & 255) << 8) | ((h2 & 255) << 16) | ((h3 & 255) << 24));
    }
    __syncthreads();
  }

  // ---- epilogue: out[31] ----
  if (wv == 0) {
    const uint4 ch = ((const uint4*)h2u)[ln & 31];
    const uint4* wo4 = (const uint4*)(wsu + WP_WO4);
    for (int j = 0; j < 10; ++j) {
      float lv = 0.f;
      if (ln < 32) {
        const uint4 w4 = wo4[j*32 + ln];
        lv = FDOT2(w4.x, ch.x, lv); lv = FDOT2(w4.y, ch.y, lv);
        lv = FDOT2(w4.z, ch.z, lv); lv = FDOT2(w4.w, ch.w, lv);
      }
      WRED(lv);
      if (!ln) sm[SH_B10 + j] = lv + bo[j];
    }
    out_lse(sm + SH_B10, out, 31, bb, ln);
  }
}

extern "C" void kernel_launch(void* const* d_in, const int* in_sizes, int n_in,
                              void* d_out, int out_size, void* d_ws, size_t ws_size,
                              hipStream_t stream) {
  (void)in_sizes; (void)n_in; (void)out_size; (void)ws_size;
  const float* batch = (const float*)d_in[0];
  const float* Wi    = (const float*)d_in[1];
  const float* bi    = (const float*)d_in[2];
  const float* Wh    = (const float*)d_in[3];
  const float* bh    = (const float*)d_in[4];
  const float* Wm    = (const float*)d_in[5];
  const float* bm    = (const float*)d_in[6];
  const float* Wo    = (const float*)d_in[7];
  const float* bo    = (const float*)d_in[8];
  const float* maddr = (const float*)d_in[9];
  const float* Wq    = (const float*)d_in[10];
  const float* bq    = (const float*)d_in[11];
  const float* us    = (const float*)d_in[12];
  const float* Wch   = (const float*)d_in[13];
  const float* Wci   = (const float*)d_in[14];
  u32* wsu  = (u32*)d_ws;
  float* out = (float*)d_out;

  hipFuncSetAttribute((const void*)dntm_step,
                      hipFuncAttributeMaxDynamicSharedMemorySize, 163840);

  pack_weights<<<53, 256, 0, stream>>>(batch, Wi, Wh, Wm, Wq, Wch, Wci, maddr, Wo, wsu);
  dntm_step<<<32, 1024, SMEM_BYTES, stream>>>(bi, bh, bm, bo, bq, us, wsu, out);
}